// Round 8
// baseline (698.656 us; speedup 1.0000x reference)
//
#include <hip/hip_runtime.h>
#include <hip/hip_bf16.h>

#define RES   100
#define ITERS 1000
#define SLOTP 128            // floats per LDS boundary-column slot

// ---------------- fused MLP layers 1-3 (round-0 exact) ----------------
__global__ __launch_bounds__(256) void mlp123(const float* __restrict__ pores,
                                              const float* __restrict__ W1, const float* __restrict__ b1,
                                              const float* __restrict__ W2, const float* __restrict__ b2,
                                              const float* __restrict__ W3, const float* __restrict__ b3,
                                              float* __restrict__ x3out) {
    __shared__ float x1[128];
    __shared__ float x2[256];
    const int s = blockIdx.x, tid = threadIdx.x;

    if (tid < 128) {
        float acc = b1[tid];
#pragma unroll
        for (int k = 0; k < 25; ++k)
            acc = fmaf(pores[s * 25 + k], W1[k * 128 + tid], acc);
        x1[tid] = fmaxf(acc, 0.0f);
    }
    __syncthreads();

    {
        float acc = b2[tid];
#pragma unroll 8
        for (int k = 0; k < 128; ++k)
            acc = fmaf(x1[k], W2[k * 256 + tid], acc);
        x2[tid] = fmaxf(acc, 0.0f);
    }
    __syncthreads();

    {
        float a0 = b3[tid], a1 = b3[tid + 256];
#pragma unroll 8
        for (int k = 0; k < 256; ++k) {
            float xv = x2[k];
            a0 = fmaf(xv, W3[k * 512 + tid],       a0);
            a1 = fmaf(xv, W3[k * 512 + tid + 256], a1);
        }
        x3out[s * 512 + tid]       = fmaxf(a0, 0.0f);
        x3out[s * 512 + tid + 256] = fmaxf(a1, 0.0f);
    }
}

// ---------------- layer 4 (round-0 exact): gen + residual + clamp ----------------
__global__ __launch_bounds__(256) void fc4_fused(const float* __restrict__ X3,
                                                 const float* __restrict__ W4,
                                                 const float* __restrict__ b4,
                                                 const float* __restrict__ pores,
                                                 float* __restrict__ cond) {
    const int j = blockIdx.x * 256 + threadIdx.x;
    if (j >= RES * RES) return;
    const int bg = blockIdx.y;
    const float* x = X3 + bg * 8 * 512;      // uniform-address reads -> SMEM path

    float acc[8];
    float bj = b4[j];
#pragma unroll
    for (int b = 0; b < 8; ++b) acc[b] = bj;

    for (int k0 = 0; k0 < 512; k0 += 8) {
        float w[8];
#pragma unroll
        for (int u = 0; u < 8; ++u)
            w[u] = W4[(k0 + u) * (RES * RES) + j];
#pragma unroll
        for (int u = 0; u < 8; ++u) {
#pragma unroll
            for (int b = 0; b < 8; ++b)
                acc[b] = fmaf(x[b * 512 + k0 + u], w[u], acc[b]);
        }
    }

    const int row = j / RES, col = j % RES;
    const int p = (row / 20) * 5 + (col / 20);
#pragma unroll
    for (int b = 0; b < 8; ++b) {
        int bb = bg * 8 + b;
        float base = 1.0f - pores[bb * 25 + p];
        cond[bb * RES * RES + j] = fmaxf(acc[b] + base, 0.01f);
    }
}

// ---------------- Jacobi solve: TRANSPOSED layout, fully scalarized ----------------
// Lanes span ROWS (Dirichlet axis): lane l holds rows (2l, 2l+1) as SCALARS lo/hi.
// Waves span COLUMNS: wave w owns R columns (4x7 + 12x6 = 100).
// No vf2 pair-adjacency: DPP results feed FMAs directly, LDS as 2x b32.
__device__ __forceinline__ float dpp_shr1_z(float src) {  // lane l <- src[l-1], OOB -> 0
    return __int_as_float(__builtin_amdgcn_update_dpp(
        0, __float_as_int(src), 0x138, 0xf, 0xf, true));
}
__device__ __forceinline__ float dpp_shl1_z(float src) {  // lane l <- src[l+1], OOB -> 0
    return __int_as_float(__builtin_amdgcn_update_dpp(
        0, __float_as_int(src), 0x130, 0xf, 0xf, true));
}

// Per column, per cell: out = C + wP*dpp + wT*partner + wW*west + wE*east
// (C=0 for hi cells -> plain mul seed; fma(a,b,0)==a*b so order is bit-stable)
template<int R>
__device__ __forceinline__ void jstepS(const float* __restrict__ wptr, const float* __restrict__ eptr,
                                       float* __restrict__ topptr, float* __restrict__ botptr,
                                       const float* wWl, const float* wWh,
                                       const float* wEl, const float* wEh,
                                       const float* wPl, const float* wPh,
                                       const float* wTl, const float* wTh,
                                       const float* Cl,
                                       const float* Til, const float* Tih,
                                       float* Tol, float* Toh) {
    float wvl = wptr[0], wvh = wptr[1];
    float evl = eptr[0], evh = eptr[1];
#pragma unroll
    for (int r = 0; r < R; ++r) {
        float wl = (r == 0)     ? wvl : Til[r - 1];
        float wh = (r == 0)     ? wvh : Tih[r - 1];
        float el = (r == R - 1) ? evl : Til[r + 1];
        float eh = (r == R - 1) ? evh : Tih[r + 1];
        float nlo = dpp_shr1_z(Tih[r]);            // north of lo = hi of lane l-1
        float shi = dpp_shl1_z(Til[r]);            // south of hi = lo of lane l+1
        Tol[r] = fmaf(wEl[r], el, fmaf(wWl[r], wl, fmaf(wTl[r], Tih[r], fmaf(wPl[r], nlo, Cl[r]))));
        Toh[r] = fmaf(wEh[r], eh, fmaf(wWh[r], wh, fmaf(wTh[r], Til[r], wPh[r] * shi)));
        if (r == 0) { topptr[0] = Tol[0]; topptr[1] = Toh[0]; }  // early store: latency hides
    }
    botptr[0] = Tol[R - 1];
    botptr[1] = Toh[R - 1];
}

__global__ __launch_bounds__(1024) void jacobi(const float* __restrict__ cond,
                                               float* __restrict__ kappa_out) {
    __shared__ float kst[RES * RES];
    __shared__ float SA[32 * SLOTP];
    __shared__ float SB[32 * SLOTP];
    __shared__ float red[16];

    const int b   = blockIdx.x;
    const int tid = threadIdx.x;

    for (int i = tid; i < RES * RES; i += 1024)
        kst[i] = cond[b * RES * RES + i];
    __syncthreads();

    const int w    = tid >> 6;
    const int lane = tid & 63;
    const int R    = (w < 4) ? 7 : 6;
    const int c0   = (w < 4) ? 7 * w : 28 + 6 * (w - 4);
    const int l    = min(lane, 49);
    const int i0   = 2 * l, i1 = 2 * l + 1;
    const int lane2 = 2 * lane;

    float wWl[7], wWh[7], wEl[7], wEh[7], wPl[7], wPh[7], wTl[7], wTh[7], Cl[7];
    float T0l[7], T0h[7], T1l[7], T1h[7];

#pragma unroll
    for (int r = 0; r < 7; ++r) {
        if (r < R) {
            int c   = c0 + r;
            int in_ = i0 ? i0 - 1 : 0;                 // north clamp (edge-pad k)
            int is_ = (i1 < RES - 1) ? i1 + 1 : RES - 1;
            int jw  = c ? c - 1 : 0;
            int je  = (c < RES - 1) ? c + 1 : RES - 1;
            float kc0 = kst[i0 * RES + c], kc1 = kst[i1 * RES + c];
            float kn0 = 0.5f * (kc0 + kst[in_ * RES + c]);
            float ks0 = 0.5f * (kc0 + kc1);            // south of i0 = i1
            float kw0 = 0.5f * (kc0 + kst[i0 * RES + jw]);
            float ke0 = 0.5f * (kc0 + kst[i0 * RES + je]);
            float kn1 = 0.5f * (kc1 + kc0);            // north of i1 = i0
            float ks1 = 0.5f * (kc1 + kst[is_ * RES + c]);
            float kw1 = 0.5f * (kc1 + kst[i1 * RES + jw]);
            float ke1 = 0.5f * (kc1 + kst[i1 * RES + je]);
            float inv0 = 1.0f / (kn0 + ks0 + kw0 + ke0 + 1e-12f);
            float inv1 = 1.0f / (kn1 + ks1 + kw1 + ke1 + 1e-12f);
            wWl[r] = kw0 * inv0;  wWh[r] = kw1 * inv1;
            wEl[r] = ke0 * inv0;  wEh[r] = ke1 * inv1;
            wPl[r] = (l == 0)  ? 0.0f : kn0 * inv0;    // DPP weight, virtual-edge zeroed
            wPh[r] = (l >= 49) ? 0.0f : ks1 * inv1;
            wTl[r] = ks0 * inv0;                       // partner: south of lo = hi
            wTh[r] = kn1 * inv1;                       // partner: north of hi = lo
            Cl[r]  = (l == 0) ? kn0 * inv0 : 0.0f;     // virtual north row T=1 seed
            T0l[r] = 1.0f - (float)i0 * (1.0f / (RES - 1));
            T0h[r] = 1.0f - (float)i1 * (1.0f / (RES - 1));
        }
    }

    // publish initial boundary columns into SA
    {
        float botl = (w < 4) ? T0l[6] : T0l[5];
        float both = (w < 4) ? T0h[6] : T0h[5];
        float* tp = SA + (2 * w) * SLOTP + lane2;
        float* bp = SA + (2 * w + 1) * SLOTP + lane2;
        tp[0] = T0l[0];  tp[1] = T0h[0];
        bp[0] = botl;    bp[1] = both;
    }
    __syncthreads();

    // west input: west-neighbor's bot slot; wave 0 reads its OWN top (Neumann self)
    // east input: east-neighbor's top slot; wave 15 reads its OWN bot
    const int wslot = (w == 0)  ? 0  : (2 * w - 1);
    const int eslot = (w == 15) ? 31 : (2 * w + 2);
    const int topsl = 2 * w;

    const float* SAw = SA + wslot * SLOTP + lane2;
    const float* SAe = SA + eslot * SLOTP + lane2;
    const float* SBw = SB + wslot * SLOTP + lane2;
    const float* SBe = SB + eslot * SLOTP + lane2;
    float* SAtop = SA + topsl * SLOTP + lane2;
    float* SAbot = SA + (topsl + 1) * SLOTP + lane2;
    float* SBtop = SB + topsl * SLOTP + lane2;
    float* SBbot = SB + (topsl + 1) * SLOTP + lane2;

    for (int it = 0; it < ITERS / 2; ++it) {
        if (w < 4) jstepS<7>(SAw, SAe, SBtop, SBbot, wWl, wWh, wEl, wEh, wPl, wPh, wTl, wTh, Cl, T0l, T0h, T1l, T1h);
        else       jstepS<6>(SAw, SAe, SBtop, SBbot, wWl, wWh, wEl, wEh, wPl, wPh, wTl, wTh, Cl, T0l, T0h, T1l, T1h);
        __syncthreads();
        if (w < 4) jstepS<7>(SBw, SBe, SAtop, SAbot, wWl, wWh, wEl, wEh, wPl, wPh, wTl, wTh, Cl, T1l, T1h, T0l, T0h);
        else       jstepS<6>(SBw, SBe, SAtop, SAbot, wWl, wWh, wEl, wEh, wPl, wPh, wTl, wTh, Cl, T1l, T1h, T0l, T0h);
        __syncthreads();
    }

    // kappa = 2 * sum_j k[0][j]*(1 - T[0][j]); row 0 lives in lane 0's lo
    if (lane == 0) {
        float part = 0.0f;
#pragma unroll
        for (int r = 0; r < 7; ++r)
            if (r < R) part = fmaf(kst[c0 + r], 1.0f - T0l[r], part);
        red[w] = part;
    }
    __syncthreads();
    if (tid == 0) {
        float s = 0.0f;
#pragma unroll
        for (int i = 0; i < 16; ++i) s += red[i];
        kappa_out[b] = 2.0f * s;
    }
}

extern "C" void kernel_launch(void* const* d_in, const int* in_sizes, int n_in,
                              void* d_out, int out_size, void* d_ws, size_t ws_size,
                              hipStream_t stream) {
    (void)in_sizes; (void)n_in; (void)out_size; (void)ws_size;
    const float* pores = (const float*)d_in[0];
    const float* W1 = (const float*)d_in[1];
    const float* b1 = (const float*)d_in[2];
    const float* W2 = (const float*)d_in[3];
    const float* b2 = (const float*)d_in[4];
    const float* W3 = (const float*)d_in[5];
    const float* b3 = (const float*)d_in[6];
    const float* W4 = (const float*)d_in[7];
    const float* b4 = (const float*)d_in[8];

    float* x3 = (float*)d_ws;               // 32*512

    float* kappa = (float*)d_out;           // 32
    float* cond  = kappa + 32;              // 32*100*100

    mlp123<<<32, 256, 0, stream>>>(pores, W1, b1, W2, b2, W3, b3, x3);
    fc4_fused<<<dim3(40, 4), 256, 0, stream>>>(x3, W4, b4, pores, cond);
    jacobi<<<32, 1024, 0, stream>>>(cond, kappa);
}

// Round 9
// 544.594 us; speedup vs baseline: 1.2829x; 1.2829x over previous
//
#include <hip/hip_runtime.h>
#include <hip/hip_bf16.h>

#define RES   100
#define ITERS 1000
#define SLOTP 128            // floats per LDS boundary-column slot

typedef float vf2 __attribute__((ext_vector_type(2)));

// ---------------- fused MLP layers 1-3 (round-0 exact) ----------------
__global__ __launch_bounds__(256) void mlp123(const float* __restrict__ pores,
                                              const float* __restrict__ W1, const float* __restrict__ b1,
                                              const float* __restrict__ W2, const float* __restrict__ b2,
                                              const float* __restrict__ W3, const float* __restrict__ b3,
                                              float* __restrict__ x3out) {
    __shared__ float x1[128];
    __shared__ float x2[256];
    const int s = blockIdx.x, tid = threadIdx.x;

    if (tid < 128) {
        float acc = b1[tid];
#pragma unroll
        for (int k = 0; k < 25; ++k)
            acc = fmaf(pores[s * 25 + k], W1[k * 128 + tid], acc);
        x1[tid] = fmaxf(acc, 0.0f);
    }
    __syncthreads();

    {
        float acc = b2[tid];
#pragma unroll 8
        for (int k = 0; k < 128; ++k)
            acc = fmaf(x1[k], W2[k * 256 + tid], acc);
        x2[tid] = fmaxf(acc, 0.0f);
    }
    __syncthreads();

    {
        float a0 = b3[tid], a1 = b3[tid + 256];
#pragma unroll 8
        for (int k = 0; k < 256; ++k) {
            float xv = x2[k];
            a0 = fmaf(xv, W3[k * 512 + tid],       a0);
            a1 = fmaf(xv, W3[k * 512 + tid + 256], a1);
        }
        x3out[s * 512 + tid]       = fmaxf(a0, 0.0f);
        x3out[s * 512 + tid + 256] = fmaxf(a1, 0.0f);
    }
}

// ---------------- layer 4 (round-0 exact): gen + residual + clamp ----------------
__global__ __launch_bounds__(256) void fc4_fused(const float* __restrict__ X3,
                                                 const float* __restrict__ W4,
                                                 const float* __restrict__ b4,
                                                 const float* __restrict__ pores,
                                                 float* __restrict__ cond) {
    const int j = blockIdx.x * 256 + threadIdx.x;
    if (j >= RES * RES) return;
    const int bg = blockIdx.y;
    const float* x = X3 + bg * 8 * 512;      // uniform-address reads -> SMEM path

    float acc[8];
    float bj = b4[j];
#pragma unroll
    for (int b = 0; b < 8; ++b) acc[b] = bj;

    for (int k0 = 0; k0 < 512; k0 += 8) {
        float w[8];
#pragma unroll
        for (int u = 0; u < 8; ++u)
            w[u] = W4[(k0 + u) * (RES * RES) + j];
#pragma unroll
        for (int u = 0; u < 8; ++u) {
#pragma unroll
            for (int b = 0; b < 8; ++b)
                acc[b] = fmaf(x[b * 512 + k0 + u], w[u], acc[b]);
        }
    }

    const int row = j / RES, col = j % RES;
    const int p = (row / 20) * 5 + (col / 20);
#pragma unroll
    for (int b = 0; b < 8; ++b) {
        int bb = bg * 8 + b;
        float base = 1.0f - pores[bb * 25 + p];
        cond[bb * RES * RES + j] = fmaxf(acc[b] + base, 0.01f);
    }
}

// ---------------- Jacobi solve: TRANSPOSED layout (r7) + early top-store ----------------
// Lanes span ROWS (Dirichlet axis): lane l holds rows (2l, 2l+1) packed in vf2.
// Waves span COLUMNS: wave w owns R columns (4 waves x 7 + 12 waves x 6 = 100).
// N/S neighbors: in-lane swap + DPP (bound_ctrl=1, no old_v movs).
// Virtual Dirichlet rows: constant seed C, edge DPP weight zeroed.
// E/W (Neumann) columns: LDS slot exchange; edge waves read their OWN slot.
__device__ __forceinline__ float dpp_shr1_z(float src) {  // lane l <- src[l-1], OOB -> 0
    return __int_as_float(__builtin_amdgcn_update_dpp(
        0, __float_as_int(src), 0x138, 0xf, 0xf, true));
}
__device__ __forceinline__ float dpp_shl1_z(float src) {  // lane l <- src[l+1], OOB -> 0
    return __int_as_float(__builtin_amdgcn_update_dpp(
        0, __float_as_int(src), 0x130, 0xf, 0xf, true));
}

// c = {T[i0,col], T[i1,col]}; wv/ev = west/east column vf2.
// P  = {north-of-lo, south-of-hi} (DPP), TS = {hi, lo} (in-lane N/S).
// .x order: C + kN*N + kS*S + kW*W + kE*E  == reference order.
__device__ __forceinline__ vf2 jrowT(vf2 wv, vf2 ev, vf2 c,
                                     vf2 wWr, vf2 wEr, vf2 wPr, vf2 wTr, vf2 Cr) {
    float nlo = dpp_shr1_z(c.y);
    float shi = dpp_shl1_z(c.x);
    vf2 P;  P.x  = nlo; P.y  = shi;
    vf2 TS; TS.x = c.y; TS.y = c.x;
    return Cr + wPr * P + wTr * TS + wWr * wv + wEr * ev;
}

// Single delta vs r7: top-boundary store issued right after column 0 is
// computed, so its LDS-write latency drains under the remaining columns
// instead of being exposed at the pre-barrier s_waitcnt.
template<int R>
__device__ __forceinline__ void jstepT(const vf2* __restrict__ wptr, const vf2* __restrict__ eptr,
                                       vf2* __restrict__ topptr, vf2* __restrict__ botptr,
                                       const vf2* wW, const vf2* wE,
                                       const vf2* wP, const vf2* wT, const vf2* C,
                                       const vf2* Tin, vf2* Tout) {
    vf2 wval = *wptr;
    vf2 eval = *eptr;
#pragma unroll
    for (int r = 0; r < R; ++r) {
        vf2 wv = (r == 0)     ? wval : Tin[r - 1];
        vf2 ev = (r == R - 1) ? eval : Tin[r + 1];
        Tout[r] = jrowT(wv, ev, Tin[r], wW[r], wE[r], wP[r], wT[r], C[r]);
        if (r == 0) *topptr = Tout[0];     // early store: drains under cols 1..R-1
    }
    *botptr = Tout[R - 1];
}

__global__ __launch_bounds__(1024) void jacobi(const float* __restrict__ cond,
                                               float* __restrict__ kappa_out) {
    __shared__ float kst[RES * RES];
    __shared__ float SA[32 * SLOTP];
    __shared__ float SB[32 * SLOTP];
    __shared__ float red[16];

    const int b   = blockIdx.x;
    const int tid = threadIdx.x;

    for (int i = tid; i < RES * RES; i += 1024)
        kst[i] = cond[b * RES * RES + i];
    __syncthreads();

    const int w    = tid >> 6;
    const int lane = tid & 63;
    const int R    = (w < 4) ? 7 : 6;
    const int c0   = (w < 4) ? 7 * w : 28 + 6 * (w - 4);
    const int l    = min(lane, 49);
    const int i0   = 2 * l, i1 = 2 * l + 1;
    const int lane2 = 2 * lane;

    vf2 wW[7], wE[7], wP[7], wT[7], C[7], T0[7], T1[7];

#pragma unroll
    for (int r = 0; r < 7; ++r) {
        if (r < R) {
            int c  = c0 + r;
            int in_ = i0 ? i0 - 1 : 0;                 // north clamp (edge-pad k)
            int is_ = (i1 < RES - 1) ? i1 + 1 : RES - 1;
            int jw  = c ? c - 1 : 0;
            int je  = (c < RES - 1) ? c + 1 : RES - 1;
            float kc0 = kst[i0 * RES + c], kc1 = kst[i1 * RES + c];
            float kn0 = 0.5f * (kc0 + kst[in_ * RES + c]);
            float ks0 = 0.5f * (kc0 + kc1);            // south of i0 = i1
            float kw0 = 0.5f * (kc0 + kst[i0 * RES + jw]);
            float ke0 = 0.5f * (kc0 + kst[i0 * RES + je]);
            float kn1 = 0.5f * (kc1 + kc0);            // north of i1 = i0
            float ks1 = 0.5f * (kc1 + kst[is_ * RES + c]);
            float kw1 = 0.5f * (kc1 + kst[i1 * RES + jw]);
            float ke1 = 0.5f * (kc1 + kst[i1 * RES + je]);
            float inv0 = 1.0f / (kn0 + ks0 + kw0 + ke0 + 1e-12f);
            float inv1 = 1.0f / (kn1 + ks1 + kw1 + ke1 + 1e-12f);
            wW[r].x = kw0 * inv0;  wW[r].y = kw1 * inv1;
            wE[r].x = ke0 * inv0;  wE[r].y = ke1 * inv1;
            // P = {N-of-lo (DPP), S-of-hi (DPP)}: zero weight on virtual-edge lanes
            wP[r].x = (l == 0)  ? 0.0f : kn0 * inv0;
            wP[r].y = (l >= 49) ? 0.0f : ks1 * inv1;
            // TS = {S-of-lo = hi, N-of-hi = lo}
            wT[r].x = ks0 * inv0;  wT[r].y = kn1 * inv1;
            // constant seed: virtual north row (T=1) for lane 0; virtual south (T=0) adds 0
            C[r].x = (l == 0) ? kn0 * inv0 : 0.0f;
            C[r].y = 0.0f;
            T0[r].x = 1.0f - (float)i0 * (1.0f / (RES - 1));
            T0[r].y = 1.0f - (float)i1 * (1.0f / (RES - 1));
        }
    }

    // publish initial boundary columns into SA
    vf2 bot0 = (w < 4) ? T0[6] : T0[5];
    *(vf2*)(SA + (2 * w) * SLOTP + lane2)     = T0[0];
    *(vf2*)(SA + (2 * w + 1) * SLOTP + lane2) = bot0;
    __syncthreads();

    // west input: west-neighbor's bot slot; wave 0 reads its OWN top (Neumann self)
    // east input: east-neighbor's top slot; wave 15 reads its OWN bot
    const int wslot = (w == 0)  ? 0  : (2 * w - 1);
    const int eslot = (w == 15) ? 31 : (2 * w + 2);
    const int topsl = 2 * w;

    const vf2* SAw = (const vf2*)(SA + wslot * SLOTP + lane2);
    const vf2* SAe = (const vf2*)(SA + eslot * SLOTP + lane2);
    const vf2* SBw = (const vf2*)(SB + wslot * SLOTP + lane2);
    const vf2* SBe = (const vf2*)(SB + eslot * SLOTP + lane2);
    vf2* SAtop = (vf2*)(SA + topsl * SLOTP + lane2);
    vf2* SAbot = (vf2*)(SA + (topsl + 1) * SLOTP + lane2);
    vf2* SBtop = (vf2*)(SB + topsl * SLOTP + lane2);
    vf2* SBbot = (vf2*)(SB + (topsl + 1) * SLOTP + lane2);

    for (int it = 0; it < ITERS / 2; ++it) {
        if (w < 4) jstepT<7>(SAw, SAe, SBtop, SBbot, wW, wE, wP, wT, C, T0, T1);
        else       jstepT<6>(SAw, SAe, SBtop, SBbot, wW, wE, wP, wT, C, T0, T1);
        __syncthreads();
        if (w < 4) jstepT<7>(SBw, SBe, SAtop, SAbot, wW, wE, wP, wT, C, T1, T0);
        else       jstepT<6>(SBw, SBe, SAtop, SAbot, wW, wE, wP, wT, C, T1, T0);
        __syncthreads();
    }

    // kappa = 2 * sum_j k[0][j]*(1 - T[0][j]); row 0 lives in lane 0's .x
    if (lane == 0) {
        float part = 0.0f;
#pragma unroll
        for (int r = 0; r < 7; ++r)
            if (r < R) part = fmaf(kst[c0 + r], 1.0f - T0[r].x, part);
        red[w] = part;
    }
    __syncthreads();
    if (tid == 0) {
        float s = 0.0f;
#pragma unroll
        for (int i = 0; i < 16; ++i) s += red[i];
        kappa_out[b] = 2.0f * s;
    }
}

extern "C" void kernel_launch(void* const* d_in, const int* in_sizes, int n_in,
                              void* d_out, int out_size, void* d_ws, size_t ws_size,
                              hipStream_t stream) {
    (void)in_sizes; (void)n_in; (void)out_size; (void)ws_size;
    const float* pores = (const float*)d_in[0];
    const float* W1 = (const float*)d_in[1];
    const float* b1 = (const float*)d_in[2];
    const float* W2 = (const float*)d_in[3];
    const float* b2 = (const float*)d_in[4];
    const float* W3 = (const float*)d_in[5];
    const float* b3 = (const float*)d_in[6];
    const float* W4 = (const float*)d_in[7];
    const float* b4 = (const float*)d_in[8];

    float* x3 = (float*)d_ws;               // 32*512

    float* kappa = (float*)d_out;           // 32
    float* cond  = kappa + 32;              // 32*100*100

    mlp123<<<32, 256, 0, stream>>>(pores, W1, b1, W2, b2, W3, b3, x3);
    fc4_fused<<<dim3(40, 4), 256, 0, stream>>>(x3, W4, b4, pores, cond);
    jacobi<<<32, 1024, 0, stream>>>(cond, kappa);
}